// Round 2
// baseline (1692.233 us; speedup 1.0000x reference)
//
#include <hip/hip_runtime.h>

typedef __attribute__((ext_vector_type(8))) short bf16x8;
typedef __attribute__((ext_vector_type(4))) float f32x4;

#define INV_TEMP 0.08838834764831845f   // 1/sqrt(128)
#define CH_STRIDE 262144                // 512*512 floats per channel plane

static __device__ __forceinline__ unsigned short f2b(float f) {
    union { float f; unsigned int u; } v; v.f = f;
    unsigned int b = (v.u + 0x7fffu + ((v.u >> 16) & 1u)) >> 16;
    return (unsigned short)b;
}

// 8 consecutive channels (stride = one 512x512 plane) at one pixel -> A-frag octet
static __device__ __forceinline__ bf16x8 gather8(const float* p) {
    bf16x8 r;
    r[0] = (short)f2b(p[0 * CH_STRIDE]);
    r[1] = (short)f2b(p[1 * CH_STRIDE]);
    r[2] = (short)f2b(p[2 * CH_STRIDE]);
    r[3] = (short)f2b(p[3 * CH_STRIDE]);
    r[4] = (short)f2b(p[4 * CH_STRIDE]);
    r[5] = (short)f2b(p[5 * CH_STRIDE]);
    r[6] = (short)f2b(p[6 * CH_STRIDE]);
    r[7] = (short)f2b(p[7 * CH_STRIDE]);
    return r;
}

// Convert the four 128x128 fp32 weights to bf16 row-major in workspace.
__global__ void prep_weights(const float* __restrict__ Wq, const float* __restrict__ Wk,
                             const float* __restrict__ Wv, const float* __restrict__ Wo,
                             unsigned short* __restrict__ wbf) {
    int i = blockIdx.x * 256 + threadIdx.x;       // 64 blocks x 256 = 16384
    wbf[i]          = f2b(Wq[i]);
    wbf[16384 + i]  = f2b(Wk[i]);
    wbf[32768 + i]  = f2b(Wv[i]);
    wbf[49152 + i]  = f2b(Wo[i]);
}

// One block = one 16x16 patch (256 tokens, C=128). 512 threads = 8 waves,
// each wave owns 32 query tokens. No persistent patch buffer in LDS: MFMA
// A-fragments of p are gathered straight from global (coalesced 4B loads),
// so LDS = kT chunk + vT chunk + per-wave scratch = 70.7 KB -> 2 blocks/CU.
__launch_bounds__(512, 4)
__global__ void patch_attn(const float* __restrict__ x,
                           const float* __restrict__ bq, const float* __restrict__ bk,
                           const float* __restrict__ bv, const float* __restrict__ bo,
                           const unsigned short* __restrict__ wbf,
                           float* __restrict__ out)
{
    __shared__ __align__(16) unsigned short kTc[64 * 136];   // 17,408 B  [key tok][d]
    __shared__ __align__(16) unsigned short vTc[128 * 72];   // 18,432 B  [d][key tok]
    __shared__ __align__(16) unsigned short sC [8 * 16 * 136]; // 34,816 B per-wave scratch

    const int tid  = threadIdx.x;
    const int w    = tid >> 6;
    const int lane = tid & 63;
    const int quad = lane >> 4;
    const int l16  = lane & 15;

    const int pid = blockIdx.x;            // 2048 patches
    const int b   = pid >> 10;
    const int n   = pid & 1023;
    const int gy  = n >> 5, gx = n & 31;
    const long patch_off = ((long)(b * 128) * 512 + gy * 16) * 512 + gx * 16;
    const float* xp = x + patch_off;

    const unsigned short* Wq_bf = wbf;
    const unsigned short* Wk_bf = wbf + 16384;
    const unsigned short* Wv_bf = wbf + 32768;
    const unsigned short* Wo_bf = wbf + 49152;

    unsigned short* scr = sC + w * (16 * 136);   // wave-private: q/P/y round-trips

    const int lbase = w * 32;

    // ---------------- Phase 1: q-projection -> A-frag registers --------------
    bf16x8 qfrag[2][4];
#pragma unroll
    for (int lt = 0; lt < 2; ++lt) {
        const int l0 = lbase + lt * 16;
        // token = l0 + l16 -> pixel (sh = l0>>4, sw = l16)
        const float* pbase = xp + (l0 >> 4) * 512 + l16;
        bf16x8 a[4];
#pragma unroll
        for (int ks = 0; ks < 4; ++ks)
            a[ks] = gather8(pbase + (long)(ks * 32 + quad * 8) * CH_STRIDE);
#pragma unroll
        for (int dt = 0; dt < 8; ++dt) {
            f32x4 acc = {0.f, 0.f, 0.f, 0.f};
#pragma unroll
            for (int ks = 0; ks < 4; ++ks) {
                bf16x8 bb = *(const bf16x8*)(Wq_bf + (dt * 16 + l16) * 128 + ks * 32 + quad * 8);
                acc = __builtin_amdgcn_mfma_f32_16x16x32_bf16(a[ks], bb, acc, 0, 0, 0);
            }
            int d = dt * 16 + l16;
            float bias = bq[d];
#pragma unroll
            for (int r = 0; r < 4; ++r)
                scr[(quad * 4 + r) * 136 + d] = f2b((acc[r] + bias) * INV_TEMP);
        }
        // wave-private round-trip (compiler inserts lgkmcnt waits)
#pragma unroll
        for (int ks = 0; ks < 4; ++ks)
            qfrag[lt][ks] = *(const bf16x8*)&scr[l16 * 136 + ks * 32 + quad * 8];
    }

    // ---------------- Phase 2: flash over 4 key-chunks of 64 -----------------
    f32x4 O[2][8];
#pragma unroll
    for (int lt = 0; lt < 2; ++lt)
#pragma unroll
        for (int dt = 0; dt < 8; ++dt) O[lt][dt] = (f32x4){0.f, 0.f, 0.f, 0.f};
    float mrow[2][4], lrow[2][4];
#pragma unroll
    for (int lt = 0; lt < 2; ++lt)
#pragma unroll
        for (int r = 0; r < 4; ++r) { mrow[lt][r] = -1e30f; lrow[lt][r] = 0.f; }

    const int mt  = w >> 1;        // this wave's key-token 16-row within the chunk
    const int dt0 = (w & 1) * 4;   // this wave's d-tile range (4 tiles)

    for (int ch = 0; ch < 4; ++ch) {
        const int m0 = ch * 64;
        // ---- build kT [64][136] and vT [128][72] for this chunk ----
        {
            const int trow = m0 + mt * 16;                    // global key token base
            const float* pbase = xp + (trow >> 4) * 512 + l16;
            bf16x8 a[4];
#pragma unroll
            for (int ks = 0; ks < 4; ++ks)
                a[ks] = gather8(pbase + (long)(ks * 32 + quad * 8) * CH_STRIDE);
#pragma unroll
            for (int dd = 0; dd < 4; ++dd) {
                const int dt = dt0 + dd;
                f32x4 kacc = {0.f, 0.f, 0.f, 0.f}, vacc = {0.f, 0.f, 0.f, 0.f};
#pragma unroll
                for (int ks = 0; ks < 4; ++ks) {
                    bf16x8 bkf = *(const bf16x8*)(Wk_bf + (dt * 16 + l16) * 128 + ks * 32 + quad * 8);
                    kacc = __builtin_amdgcn_mfma_f32_16x16x32_bf16(a[ks], bkf, kacc, 0, 0, 0);
                    bf16x8 bvf = *(const bf16x8*)(Wv_bf + (dt * 16 + l16) * 128 + ks * 32 + quad * 8);
                    vacc = __builtin_amdgcn_mfma_f32_16x16x32_bf16(a[ks], bvf, vacc, 0, 0, 0);
                }
                const int d = dt * 16 + l16;
                const float kb = bk[d], vb = bv[d];
#pragma unroll
                for (int r = 0; r < 4; ++r)
                    kTc[(mt * 16 + quad * 4 + r) * 136 + d] = f2b(kacc[r] + kb);
                unsigned short vp[4];
#pragma unroll
                for (int r = 0; r < 4; ++r) vp[r] = f2b(vacc[r] + vb);
                unsigned long long pk = (unsigned long long)vp[0]
                                      | ((unsigned long long)vp[1] << 16)
                                      | ((unsigned long long)vp[2] << 32)
                                      | ((unsigned long long)vp[3] << 48);
                *(unsigned long long*)&vTc[d * 72 + mt * 16 + quad * 4] = pk;
            }
        }
        __syncthreads();

        // ---- S = q.kT^T, online softmax, P round-trip, O += P.v ----
#pragma unroll
        for (int lt = 0; lt < 2; ++lt) {
            f32x4 s[4];
#pragma unroll
            for (int nt = 0; nt < 4; ++nt) {
                f32x4 acc = {0.f, 0.f, 0.f, 0.f};
#pragma unroll
                for (int ks = 0; ks < 4; ++ks) {
                    bf16x8 bb = *(const bf16x8*)&kTc[(nt * 16 + l16) * 136 + ks * 32 + quad * 8];
                    acc = __builtin_amdgcn_mfma_f32_16x16x32_bf16(qfrag[lt][ks], bb, acc, 0, 0, 0);
                }
                s[nt] = acc;
            }
#pragma unroll
            for (int r = 0; r < 4; ++r) {
                float mx = fmaxf(fmaxf(s[0][r], s[1][r]), fmaxf(s[2][r], s[3][r]));
#pragma unroll
                for (int off = 8; off; off >>= 1) mx = fmaxf(mx, __shfl_xor(mx, off));
                float mnew  = fmaxf(mrow[lt][r], mx);
                float alpha = __expf(mrow[lt][r] - mnew);
                mrow[lt][r] = mnew;
                float rs = 0.f;
#pragma unroll
                for (int nt = 0; nt < 4; ++nt) {
                    float p = __expf(s[nt][r] - mnew);
                    s[nt][r] = p;
                    rs += p;
                }
#pragma unroll
                for (int off = 8; off; off >>= 1) rs += __shfl_xor(rs, off);
                lrow[lt][r] = lrow[lt][r] * alpha + rs;
#pragma unroll
                for (int dt = 0; dt < 8; ++dt) O[lt][dt][r] *= alpha;
            }
            // P: C-layout -> A-layout via wave-private scratch (stride 72)
#pragma unroll
            for (int nt = 0; nt < 4; ++nt)
#pragma unroll
                for (int r = 0; r < 4; ++r)
                    scr[(quad * 4 + r) * 72 + nt * 16 + l16] = f2b(s[nt][r]);
#pragma unroll
            for (int dt = 0; dt < 8; ++dt) {
                f32x4 acc = O[lt][dt];
#pragma unroll
                for (int kt = 0; kt < 2; ++kt) {
                    bf16x8 pa = *(const bf16x8*)&scr[l16 * 72 + kt * 32 + quad * 8];
                    bf16x8 vb = *(const bf16x8*)&vTc[(dt * 16 + l16) * 72 + kt * 32 + quad * 8];
                    acc = __builtin_amdgcn_mfma_f32_16x16x32_bf16(pa, vb, acc, 0, 0, 0);
                }
                O[lt][dt] = acc;
            }
        }
        __syncthreads();   // kTc/vTc consumed; safe to overwrite next chunk
    }

    // ---------------- Phase 3: normalize, O-proj, residual, float4 store -----
#pragma unroll
    for (int lt = 0; lt < 2; ++lt) {
        float inv[4];
#pragma unroll
        for (int r = 0; r < 4; ++r) inv[r] = 1.f / lrow[lt][r];
#pragma unroll
        for (int dt = 0; dt < 8; ++dt)
#pragma unroll
            for (int r = 0; r < 4; ++r)
                scr[(quad * 4 + r) * 136 + dt * 16 + l16] = f2b(O[lt][dt][r] * inv[r]);
        bf16x8 a[4];
#pragma unroll
        for (int ks = 0; ks < 4; ++ks)
            a[ks] = *(const bf16x8*)&scr[l16 * 136 + ks * 32 + quad * 8];

        const int sh = w * 2 + lt;   // local pixel row of this lt-slice
#pragma unroll
        for (int ct = 0; ct < 8; ++ct) {
            f32x4 acc = {0.f, 0.f, 0.f, 0.f};
#pragma unroll
            for (int ks = 0; ks < 4; ++ks) {
                bf16x8 bb = *(const bf16x8*)(Wo_bf + (ct * 16 + l16) * 128 + ks * 32 + quad * 8);
                acc = __builtin_amdgcn_mfma_f32_16x16x32_bf16(a[ks], bb, acc, 0, 0, 0);
            }
            const int c = ct * 16 + l16;
            const float bias = bo[c];
            const long poff = patch_off + (long)c * CH_STRIDE + sh * 512 + quad * 4;
            const float4 rv = *(const float4*)(x + poff);
            float4 ov;
            ov.x = acc[0] + bias + rv.x;
            ov.y = acc[1] + bias + rv.y;
            ov.z = acc[2] + bias + rv.z;
            ov.w = acc[3] + bias + rv.w;
            *(float4*)(out + poff) = ov;
        }
    }
}

extern "C" void kernel_launch(void* const* d_in, const int* in_sizes, int n_in,
                              void* d_out, int out_size, void* d_ws, size_t ws_size,
                              hipStream_t stream) {
    (void)in_sizes; (void)n_in; (void)out_size; (void)ws_size;
    const float* x  = (const float*)d_in[0];
    const float* Wq = (const float*)d_in[1];
    const float* bq = (const float*)d_in[2];
    const float* Wk = (const float*)d_in[3];
    const float* bk = (const float*)d_in[4];
    const float* Wv = (const float*)d_in[5];
    const float* bv = (const float*)d_in[6];
    const float* Wo = (const float*)d_in[7];
    const float* bo = (const float*)d_in[8];
    unsigned short* wbf = (unsigned short*)d_ws;   // 131,072 B of bf16 weights

    prep_weights<<<64, 256, 0, stream>>>(Wq, Wk, Wv, Wo, wbf);
    patch_attn<<<2048, 512, 0, stream>>>(x, bq, bk, bv, bo, wbf, (float*)d_out);
}